// Round 4
// baseline (104.411 us; speedup 1.0000x reference)
//
#include <hip/hip_runtime.h>

#define NPATCH 16384
#define NDB    16384
#define WS9    9
#define KP     16               // K padded 9 -> 16 for 32x32x16 MFMA
#define GSL    16               // j-slices (grid.y of k_dot)
#define SLROWS (NDB / GSL)      // 1024 db rows per slice
#define NT     (SLROWS / 32)    // 32 j-tiles per slice
// Split-bf16 cosmax error vs numpy fp32 path <= ~6e-6. Band +-2e-5 keeps 3x
// margin; band population ~= 80 patches -> phase2 recheck is cheap.
#define BAND_LO 0.89998f
#define BAND_HI 0.90002f
#define COPY_BLOCKS 144         // NDB*9/4/256 float4-copy blocks
#define PREP_BLOCKS 144         // 36864 threads: 32768 stage rows + copy

typedef short bf16x8 __attribute__((ext_vector_type(8)));
typedef float f32x16 __attribute__((ext_vector_type(16)));

#define MAX3(a,b,c) fmaxf(fmaxf((a),(b)),(c))

// numpy-order norm of 9 elements: sqrt(pairwise-8 + remainder), no contraction.
__device__ __forceinline__ float np_norm9(const float* v) {
#pragma clang fp contract(off)
    float q0 = v[0] * v[0], q1 = v[1] * v[1], q2 = v[2] * v[2], q3 = v[3] * v[3];
    float q4 = v[4] * v[4], q5 = v[5] * v[5], q6 = v[6] * v[6], q7 = v[7] * v[7];
    float q8 = v[8] * v[8];
    float s = ((q0 + q1) + (q2 + q3)) + ((q4 + q5) + (q6 + q7));
    s = s + q8;
    return sqrtf(s);
}

// fp32 -> bf16 RTNE (no NaN inputs here), and back
__device__ __forceinline__ unsigned short f2bf(float x) {
    unsigned u = __float_as_uint(x);
    return (unsigned short)((u + 0x7fffu + ((u >> 16) & 1u)) >> 16);
}
__device__ __forceinline__ float bf2f(unsigned short h) {
    return __uint_as_float(((unsigned)h) << 16);
}

// load row of 9, normalize, split to bf16 hi/lo, K-pad to 16, pack 2x int4 per
// array. Bit-identical to the proven staging (absmax=0 in all prior rounds).
__device__ __forceinline__ void stage_row(const float* __restrict__ src,
                                          unsigned short* dh, unsigned short* dl) {
    float v[WS9];
#pragma unroll
    for (int k = 0; k < WS9; k++) v[k] = src[k];
    float inv = 1.0f / np_norm9(v);
    unsigned short h[KP], l[KP];
#pragma unroll
    for (int k = 0; k < KP; k++) {
        float x = (k < WS9) ? v[k] * inv : 0.0f;
        h[k] = f2bf(x);
        l[k] = f2bf(x - bf2f(h[k]));
    }
    int hw[8], lw[8];
#pragma unroll
    for (int k = 0; k < 8; k++) {
        hw[k] = (int)h[2 * k] | ((int)h[2 * k + 1] << 16);
        lw[k] = (int)l[2 * k] | ((int)l[2 * k + 1] << 16);
    }
    ((int4*)dh)[0] = make_int4(hw[0], hw[1], hw[2], hw[3]);
    ((int4*)dh)[1] = make_int4(hw[4], hw[5], hw[6], hw[7]);
    ((int4*)dl)[0] = make_int4(lw[0], lw[1], lw[2], lw[3]);
    ((int4*)dl)[1] = make_int4(lw[4], lw[5], lw[6], lw[7]);
}

// K0: one-shot prep. Normalize+split every row once into the MFMA-fragment
// global layout (row r -> two 16B frags at index r*2+half), db->out copy,
// band_count init. Rounds 1/3 proved staging cost/location is off the
// critical path; what matters is that k_dot below has NO LDS and NO barrier.
__global__ __launch_bounds__(256) void k_prep(const float* __restrict__ patches,
                                              const float* __restrict__ db,
                                              unsigned short* __restrict__ pnh,
                                              unsigned short* __restrict__ pnl,
                                              unsigned short* __restrict__ dnh,
                                              unsigned short* __restrict__ dnl,
                                              float* __restrict__ out,
                                              int* __restrict__ band_count) {
    int t = blockIdx.x * 256 + threadIdx.x;       // [0, 36864)
    if (t == 0) *band_count = 0;
    // db -> out rows [0, NDB): 147456 floats = 36864 float4
    ((float4*)out)[t] = ((const float4*)db)[t];
    if (t < NPATCH) {
        stage_row(patches + (size_t)t * WS9, &pnh[(size_t)t * KP], &pnl[(size_t)t * KP]);
    } else if (t < 2 * NPATCH) {
        int r = t - NPATCH;
        stage_row(db + (size_t)r * WS9, &dnh[(size_t)r * KP], &dnl[(size_t)r * KP]);
    }
}

// K1: barrier-free, LDS-free dot kernel. Grid 64 patch-groups x 16 db-slices
// = 1024 blocks = 4/CU, ALL resident (no generations, no convoy). Each wave:
// 4 b-frag loads, then a register ping-pong loop of {2 coalesced 16B global
// loads (L2-resident, 64 MB total) + 6 MFMA + max3 tree}. Same bf16 values,
// same MFMA sequence, max associative -> bit-identical cosmax.
__global__ __launch_bounds__(256) void k_dot(const unsigned short* __restrict__ pnh,
                                             const unsigned short* __restrict__ pnl,
                                             const unsigned short* __restrict__ dnh,
                                             const unsigned short* __restrict__ dnl,
                                             float* __restrict__ partial) {
    int lane = threadIdx.x & 63;
    int wave = threadIdx.x >> 6;
    int col = lane & 31;
    int half = lane >> 5;
    int i0 = blockIdx.x * 256 + wave * 64;
    int rowbase = blockIdx.y * SLROWS;

    const bf16x8* Ph = (const bf16x8*)pnh;        // frag index = row*2 + half
    const bf16x8* Pl = (const bf16x8*)pnl;
    bf16x8 b_hi0 = Ph[(i0 + col) * 2 + half];
    bf16x8 b_lo0 = Pl[(i0 + col) * 2 + half];
    bf16x8 b_hi1 = Ph[(i0 + 32 + col) * 2 + half];
    bf16x8 b_lo1 = Pl[(i0 + 32 + col) * 2 + half];

    const bf16x8* Ah = (const bf16x8*)dnh;
    const bf16x8* Al = (const bf16x8*)dnl;
#define AH(tt) Ah[(rowbase + (tt) * 32 + col) * 2 + half]
#define AL(tt) Al[(rowbase + (tt) * 32 + col) * 2 + half]

    f32x16 zc = {0.f,0.f,0.f,0.f,0.f,0.f,0.f,0.f,0.f,0.f,0.f,0.f,0.f,0.f,0.f,0.f};
    float rm0 = -3.0e38f, rm1 = -3.0e38f;

    // register double-buffer, 2 tiles in flight (dnh/dnl padded by 64 rows so
    // the tt=NT..NT+1 prefetches are safe; values never consumed)
    bf16x8 ah0 = AH(0), al0 = AL(0);
    bf16x8 ah1 = AH(1), al1 = AL(1);

    for (int tt = 0; tt < NT; tt += 2) {
        bf16x8 nh0 = AH(tt + 2), nl0 = AL(tt + 2);
        {
            f32x16 acc0 = __builtin_amdgcn_mfma_f32_32x32x16_bf16(ah0, b_hi0, zc, 0, 0, 0);
            acc0 = __builtin_amdgcn_mfma_f32_32x32x16_bf16(ah0, b_lo0, acc0, 0, 0, 0);
            acc0 = __builtin_amdgcn_mfma_f32_32x32x16_bf16(al0, b_hi0, acc0, 0, 0, 0);
            f32x16 acc1 = __builtin_amdgcn_mfma_f32_32x32x16_bf16(ah0, b_hi1, zc, 0, 0, 0);
            acc1 = __builtin_amdgcn_mfma_f32_32x32x16_bf16(ah0, b_lo1, acc1, 0, 0, 0);
            acc1 = __builtin_amdgcn_mfma_f32_32x32x16_bf16(al0, b_hi1, acc1, 0, 0, 0);
            float u0 = MAX3(acc0[0],  acc0[1],  acc0[2]);
            float u1 = MAX3(acc0[3],  acc0[4],  acc0[5]);
            float u2 = MAX3(acc0[6],  acc0[7],  acc0[8]);
            float u3 = MAX3(acc0[9],  acc0[10], acc0[11]);
            float u4 = MAX3(acc0[12], acc0[13], acc0[14]);
            float u5 = MAX3(u0, u1, acc0[15]);
            float u6 = MAX3(u2, u3, u4);
            rm0 = MAX3(u5, u6, rm0);
            float w0 = MAX3(acc1[0],  acc1[1],  acc1[2]);
            float w1 = MAX3(acc1[3],  acc1[4],  acc1[5]);
            float w2 = MAX3(acc1[6],  acc1[7],  acc1[8]);
            float w3 = MAX3(acc1[9],  acc1[10], acc1[11]);
            float w4 = MAX3(acc1[12], acc1[13], acc1[14]);
            float w5 = MAX3(w0, w1, acc1[15]);
            float w6 = MAX3(w2, w3, w4);
            rm1 = MAX3(w5, w6, rm1);
        }
        bf16x8 nh1 = AH(tt + 3), nl1 = AL(tt + 3);
        {
            f32x16 acc0 = __builtin_amdgcn_mfma_f32_32x32x16_bf16(ah1, b_hi0, zc, 0, 0, 0);
            acc0 = __builtin_amdgcn_mfma_f32_32x32x16_bf16(ah1, b_lo0, acc0, 0, 0, 0);
            acc0 = __builtin_amdgcn_mfma_f32_32x32x16_bf16(al1, b_hi0, acc0, 0, 0, 0);
            f32x16 acc1 = __builtin_amdgcn_mfma_f32_32x32x16_bf16(ah1, b_hi1, zc, 0, 0, 0);
            acc1 = __builtin_amdgcn_mfma_f32_32x32x16_bf16(ah1, b_lo1, acc1, 0, 0, 0);
            acc1 = __builtin_amdgcn_mfma_f32_32x32x16_bf16(al1, b_hi1, acc1, 0, 0, 0);
            float u0 = MAX3(acc0[0],  acc0[1],  acc0[2]);
            float u1 = MAX3(acc0[3],  acc0[4],  acc0[5]);
            float u2 = MAX3(acc0[6],  acc0[7],  acc0[8]);
            float u3 = MAX3(acc0[9],  acc0[10], acc0[11]);
            float u4 = MAX3(acc0[12], acc0[13], acc0[14]);
            float u5 = MAX3(u0, u1, acc0[15]);
            float u6 = MAX3(u2, u3, u4);
            rm0 = MAX3(u5, u6, rm0);
            float w0 = MAX3(acc1[0],  acc1[1],  acc1[2]);
            float w1 = MAX3(acc1[3],  acc1[4],  acc1[5]);
            float w2 = MAX3(acc1[6],  acc1[7],  acc1[8]);
            float w3 = MAX3(acc1[9],  acc1[10], acc1[11]);
            float w4 = MAX3(acc1[12], acc1[13], acc1[14]);
            float w5 = MAX3(w0, w1, acc1[15]);
            float w6 = MAX3(w2, w3, w4);
            rm1 = MAX3(w5, w6, rm1);
        }
        ah0 = nh0; al0 = nl0; ah1 = nh1; al1 = nl1;
    }
#undef AH
#undef AL
    rm0 = fmaxf(rm0, __shfl_xor(rm0, 32, 64));
    rm1 = fmaxf(rm1, __shfl_xor(rm1, 32, 64));
    int ti = half ? (i0 + 32 + col) : (i0 + col);
    partial[(size_t)blockIdx.y * NPATCH + ti] = half ? rm1 : rm0;
}

// K2: classify: max over 16 slice-partials, definite rows written, band ->
// global list. (db->out copy lives in k_prep now.)
__global__ __launch_bounds__(256) void k_finish(const float* __restrict__ patches,
                                                const float* __restrict__ partial,
                                                float* __restrict__ out,
                                                int* __restrict__ band_list,
                                                int* __restrict__ band_count) {
    int i = blockIdx.x * 256 + threadIdx.x;
    float cosmax = partial[i];
#pragma unroll
    for (int c = 1; c < GSL; c++)
        cosmax = fmaxf(cosmax, partial[(size_t)c * NPATCH + i]);
    if (cosmax >= BAND_LO && cosmax < BAND_HI) {
        int idx = atomicAdd(band_count, 1);
        band_list[idx] = i;
        return;  // row written by phase 2
    }
    int hit = (cosmax >= BAND_HI) ? 1 : 0;
#pragma unroll
    for (int k = 0; k < WS9; k++)
        out[(size_t)(NDB + i) * WS9 + k] = hit ? 0.0f : patches[(size_t)i * WS9 + k];
}

// K3: exact numpy-mirror recheck for band patches (proven absmax=0).
__global__ __launch_bounds__(256) void k_phase2(const float* __restrict__ patches,
                                                const float* __restrict__ db,
                                                const int* __restrict__ band_list,
                                                const int* __restrict__ band_count,
                                                float* __restrict__ out) {
    __shared__ float sp[WS9];
    __shared__ float snp;
    __shared__ int shit;
    int nb = *band_count;
    for (int idx = blockIdx.x; idx < nb; idx += gridDim.x) {
        int i = band_list[idx];
        if (threadIdx.x == 0) {
            float p[WS9];
            for (int k = 0; k < WS9; k++) { p[k] = patches[(size_t)i * WS9 + k]; sp[k] = p[k]; }
            snp = np_norm9(p);
            shit = 0;
        }
        __syncthreads();
        float p[WS9];
#pragma unroll
        for (int k = 0; k < WS9; k++) p[k] = sp[k];
        float npn = snp;
        int hit = 0;
        for (int j = (int)threadIdx.x; j < NDB; j += 256) {
            float d[WS9];
#pragma unroll
            for (int k = 0; k < WS9; k++) d[k] = db[(size_t)j * WS9 + k];
            float dot = 0.0f;
#pragma unroll
            for (int k = 0; k < WS9; k++) dot = fmaf(p[k], d[k], dot);
            float nd = np_norm9(d);
            float cs = dot / (npn * nd);          // IEEE fp32 divide
            if (!((double)cs < 0.9)) hit = 1;     // numpy promotes to f64
        }
        if (hit) atomicOr(&shit, 1);
        __syncthreads();
        int m = shit;
        if (threadIdx.x < WS9)
            out[(size_t)(NDB + i) * WS9 + threadIdx.x] = m ? 0.0f : sp[threadIdx.x];
        __syncthreads();
    }
}

extern "C" void kernel_launch(void* const* d_in, const int* in_sizes, int n_in,
                              void* d_out, int out_size, void* d_ws, size_t ws_size,
                              hipStream_t stream) {
    const float* patches = (const float*)d_in[0];  // [16384][9]
    const float* db      = (const float*)d_in[1];  // [16384][9]
    float* out = (float*)d_out;                    // [32768][9]

    // ws layout: partial (GSL*NPATCH f32 = 1 MB) | band_list (64 KB) |
    // band_count (pad 256 B) | pnh | pnl | dnh | dnl (512 KB each + 4 KB pad
    // after dnh/dnl for the 2-tile prefetch overrun)
    char* wsb = (char*)d_ws;
    size_t o_partial = 0;
    size_t o_blist   = (size_t)GSL * NPATCH * 4;               // 1 MB
    size_t o_bcount  = o_blist + (size_t)NPATCH * 4;           // +64 KB
    size_t o_pnh     = o_bcount + 256;
    size_t o_pnl     = o_pnh + (size_t)NPATCH * KP * 2;        // 512 KB
    size_t o_dnh     = o_pnl + (size_t)NPATCH * KP * 2;
    size_t o_dnl     = o_dnh + (size_t)NDB * KP * 2 + 4096;    // +pad
    // (dnl also has ws tail beyond it; prefetch overrun reads poison, unused)

    float* partial      = (float*)(wsb + o_partial);
    int*   band_list    = (int*)(wsb + o_blist);
    int*   band_count   = (int*)(wsb + o_bcount);
    unsigned short* pnh = (unsigned short*)(wsb + o_pnh);
    unsigned short* pnl = (unsigned short*)(wsb + o_pnl);
    unsigned short* dnh = (unsigned short*)(wsb + o_dnh);
    unsigned short* dnl = (unsigned short*)(wsb + o_dnl);

    k_prep<<<dim3(PREP_BLOCKS), dim3(256), 0, stream>>>(patches, db, pnh, pnl,
                                                        dnh, dnl, out, band_count);
    k_dot<<<dim3(NPATCH / 256, GSL), dim3(256), 0, stream>>>(pnh, pnl, dnh, dnl,
                                                             partial);
    k_finish<<<dim3(NPATCH / 256), dim3(256), 0, stream>>>(patches, partial, out,
                                                           band_list, band_count);
    k_phase2<<<dim3(256), dim3(256), 0, stream>>>(patches, db, band_list, band_count, out);
}

// Round 5
// 96.636 us; speedup vs baseline: 1.0805x; 1.0805x over previous
//
#include <hip/hip_runtime.h>

#define NPATCH 16384
#define NDB    16384
#define WS9    9
#define KP     16               // K padded 9 -> 16 for 32x32x16 MFMA
#define JCH    32               // db chunks (grid.y)
#define CHUNK  512              // db rows per chunk
#define TILES  (CHUNK / 32)     // 16 j-tiles per chunk
#define PBLK   512              // patches per block (4 waves x 128)
// Split-bf16 cosmax error vs numpy fp32 path <= ~6e-6. Band +-2e-5 keeps 3x
// margin; band population ~= 80 patches over 64 classify groups -> inline
// recheck is ~1-2 entries per group.
#define BAND_LO 0.89998f
#define BAND_HI 0.90002f
#define COPY_BLOCKS 144         // NDB*9/4/256 float4-copy blocks

typedef short bf16x8 __attribute__((ext_vector_type(8)));
typedef float f32x16 __attribute__((ext_vector_type(16)));

#define MAX3(a,b,c) fmaxf(fmaxf((a),(b)),(c))

// numpy-order norm of 9 elements: sqrt(pairwise-8 + remainder), no contraction.
__device__ __forceinline__ float np_norm9(const float* v) {
#pragma clang fp contract(off)
    float q0 = v[0] * v[0], q1 = v[1] * v[1], q2 = v[2] * v[2], q3 = v[3] * v[3];
    float q4 = v[4] * v[4], q5 = v[5] * v[5], q6 = v[6] * v[6], q7 = v[7] * v[7];
    float q8 = v[8] * v[8];
    float s = ((q0 + q1) + (q2 + q3)) + ((q4 + q5) + (q6 + q7));
    s = s + q8;
    return sqrtf(s);
}

// fp32 -> bf16 RTNE (no NaN inputs here), and back
__device__ __forceinline__ unsigned short f2bf(float x) {
    unsigned u = __float_as_uint(x);
    return (unsigned short)((u + 0x7fffu + ((u >> 16) & 1u)) >> 16);
}
__device__ __forceinline__ float bf2f(unsigned short h) {
    return __uint_as_float(((unsigned)h) << 16);
}

// load row of 9, normalize, split to bf16 hi/lo, K-pad to 16, pack 2x int4 per
// array; also return the exact numpy norm. Math bit-identical to the proven
// staging (absmax=0 in all prior rounds).
__device__ __forceinline__ void stage_row(const float* __restrict__ src,
                                          unsigned short* dh, unsigned short* dl,
                                          float* nrm_out) {
    float v[WS9];
#pragma unroll
    for (int k = 0; k < WS9; k++) v[k] = src[k];
    float nrm = np_norm9(v);
    float inv = 1.0f / nrm;
    *nrm_out = nrm;
    unsigned short h[KP], l[KP];
#pragma unroll
    for (int k = 0; k < KP; k++) {
        float x = (k < WS9) ? v[k] * inv : 0.0f;
        h[k] = f2bf(x);
        l[k] = f2bf(x - bf2f(h[k]));
    }
    int hw[8], lw[8];
#pragma unroll
    for (int k = 0; k < 8; k++) {
        hw[k] = (int)h[2 * k] | ((int)h[2 * k + 1] << 16);
        lw[k] = (int)l[2 * k] | ((int)l[2 * k + 1] << 16);
    }
    ((int4*)dh)[0] = make_int4(hw[0], hw[1], hw[2], hw[3]);
    ((int4*)dh)[1] = make_int4(hw[4], hw[5], hw[6], hw[7]);
    ((int4*)dl)[0] = make_int4(lw[0], lw[1], lw[2], lw[3]);
    ((int4*)dl)[1] = make_int4(lw[4], lw[5], lw[6], lw[7]);
}

// K1: fused prep + phase1, WIDE per-wave tile. Block = 512 patches x 512-row
// db chunk (grid 32x32 = 1024 blocks, ~4 generations/CU). LDS (32 KB) is
// time-shared: stage 512 patches -> each wave reads 4 b-frag pairs (128
// patches) to registers -> barrier -> stage 512 db rows into the same buffer
// -> K-loop. Per a-frag load: 12 MFMA in 4 independent chains (2x density,
// 2x ILP vs all prior rounds). Same 3-MFMA-from-zero sequence per 32x32
// tile, max associative -> bit-identical cosmax. x==0 blocks also store the
// exact np_norm9 db norms for the merged recheck.
__global__ __launch_bounds__(256) void k_phase1(const float* __restrict__ patches,
                                                const float* __restrict__ db,
                                                float* __restrict__ partial,
                                                float* __restrict__ dbnorm) {
    __shared__ __align__(16) unsigned short s_h[CHUNK * KP];   // 16 KB
    __shared__ __align__(16) unsigned short s_l[CHUNK * KP];   // 16 KB

    int jbase = blockIdx.y * CHUNK;
    int ibase = blockIdx.x * PBLK;
    int tid = (int)threadIdx.x;

    // ---- stage 512 patches (2 rows/thread) into LDS
#pragma unroll
    for (int rr = 0; rr < PBLK / 256; rr++) {
        int r = rr * 256 + tid;
        float nrm;
        stage_row(patches + (size_t)(ibase + r) * WS9, &s_h[r * KP], &s_l[r * KP], &nrm);
    }
    __syncthreads();

    int lane = tid & 63;
    int wave = tid >> 6;
    int col = lane & 31;
    int half = lane >> 5;
    int i0 = ibase + wave * 128;

    const bf16x8* Ph = (const bf16x8*)s_h;        // frag index = row*2 + half
    const bf16x8* Pl = (const bf16x8*)s_l;
    bf16x8 bh0 = Ph[(wave * 128 +  0 + col) * 2 + half];
    bf16x8 bh1 = Ph[(wave * 128 + 32 + col) * 2 + half];
    bf16x8 bh2 = Ph[(wave * 128 + 64 + col) * 2 + half];
    bf16x8 bh3 = Ph[(wave * 128 + 96 + col) * 2 + half];
    bf16x8 bl0 = Pl[(wave * 128 +  0 + col) * 2 + half];
    bf16x8 bl1 = Pl[(wave * 128 + 32 + col) * 2 + half];
    bf16x8 bl2 = Pl[(wave * 128 + 64 + col) * 2 + half];
    bf16x8 bl3 = Pl[(wave * 128 + 96 + col) * 2 + half];
    __syncthreads();   // done reading patches; LDS free for db

    // ---- stage 512 db rows (2 rows/thread) into the same LDS
#pragma unroll
    for (int rr = 0; rr < CHUNK / 256; rr++) {
        int r = rr * 256 + tid;
        float nrm;
        stage_row(db + (size_t)(jbase + r) * WS9, &s_h[r * KP], &s_l[r * KP], &nrm);
        if (blockIdx.x == 0) dbnorm[jbase + r] = nrm;   // exact norm for recheck
    }
    __syncthreads();

    const bf16x8* Ah = (const bf16x8*)s_h;
    const bf16x8* Al = (const bf16x8*)s_l;

    f32x16 zc = {0.f,0.f,0.f,0.f,0.f,0.f,0.f,0.f,0.f,0.f,0.f,0.f,0.f,0.f,0.f,0.f};
    float rm0 = -3.0e38f, rm1 = -3.0e38f, rm2 = -3.0e38f, rm3 = -3.0e38f;

#define REDUCE(acc, rm)                                                     \
    {                                                                       \
        float u0 = MAX3(acc[0],  acc[1],  acc[2]);                          \
        float u1 = MAX3(acc[3],  acc[4],  acc[5]);                          \
        float u2 = MAX3(acc[6],  acc[7],  acc[8]);                          \
        float u3 = MAX3(acc[9],  acc[10], acc[11]);                         \
        float u4 = MAX3(acc[12], acc[13], acc[14]);                         \
        float u5 = MAX3(u0, u1, acc[15]);                                   \
        float u6 = MAX3(u2, u3, u4);                                        \
        rm = MAX3(u5, u6, rm);                                              \
    }

    for (int t = 0; t < TILES; ++t) {
        bf16x8 a_h = Ah[(t * 32 + col) * 2 + half];
        bf16x8 a_l = Al[(t * 32 + col) * 2 + half];
        // 4 independent 3-MFMA chains (hi*hi + hi*lo + lo*hi), grouped so the
        // scheduler can interleave chains while each waits on its own dep.
        f32x16 acc0 = __builtin_amdgcn_mfma_f32_32x32x16_bf16(a_h, bh0, zc, 0, 0, 0);
        f32x16 acc1 = __builtin_amdgcn_mfma_f32_32x32x16_bf16(a_h, bh1, zc, 0, 0, 0);
        f32x16 acc2 = __builtin_amdgcn_mfma_f32_32x32x16_bf16(a_h, bh2, zc, 0, 0, 0);
        f32x16 acc3 = __builtin_amdgcn_mfma_f32_32x32x16_bf16(a_h, bh3, zc, 0, 0, 0);
        acc0 = __builtin_amdgcn_mfma_f32_32x32x16_bf16(a_h, bl0, acc0, 0, 0, 0);
        acc1 = __builtin_amdgcn_mfma_f32_32x32x16_bf16(a_h, bl1, acc1, 0, 0, 0);
        acc2 = __builtin_amdgcn_mfma_f32_32x32x16_bf16(a_h, bl2, acc2, 0, 0, 0);
        acc3 = __builtin_amdgcn_mfma_f32_32x32x16_bf16(a_h, bl3, acc3, 0, 0, 0);
        acc0 = __builtin_amdgcn_mfma_f32_32x32x16_bf16(a_l, bh0, acc0, 0, 0, 0);
        acc1 = __builtin_amdgcn_mfma_f32_32x32x16_bf16(a_l, bh1, acc1, 0, 0, 0);
        acc2 = __builtin_amdgcn_mfma_f32_32x32x16_bf16(a_l, bh2, acc2, 0, 0, 0);
        acc3 = __builtin_amdgcn_mfma_f32_32x32x16_bf16(a_l, bh3, acc3, 0, 0, 0);
        REDUCE(acc0, rm0)
        REDUCE(acc1, rm1)
        REDUCE(acc2, rm2)
        REDUCE(acc3, rm3)
    }
#undef REDUCE

    rm0 = fmaxf(rm0, __shfl_xor(rm0, 32, 64));
    rm1 = fmaxf(rm1, __shfl_xor(rm1, 32, 64));
    rm2 = fmaxf(rm2, __shfl_xor(rm2, 32, 64));
    rm3 = fmaxf(rm3, __shfl_xor(rm3, 32, 64));
    // post-shfl both halves hold identical rm_g; half0 writes groups 0,1 and
    // half1 writes groups 2,3 (constant indices -> no scratch).
    float w0 = half ? rm2 : rm0;
    float w1 = half ? rm3 : rm1;
    int t0 = half ? (i0 + 64 + col) : (i0 + col);
    int t1 = half ? (i0 + 96 + col) : (i0 + 32 + col);
    size_t prow = (size_t)blockIdx.y * NPATCH;
    partial[prow + t0] = w0;
    partial[prow + t1] = w1;
}

// K2: merged finish. Blocks [0,144): db->out float4 copy. Blocks [144,208):
// classify 256 patches (max over 32 chunk-partials), write definite rows,
// and recheck this block's own band entries inline with the exact
// numpy-mirror path (dbnorm gives norm_m computed once, as numpy does).
__global__ __launch_bounds__(256) void k_finish(const float* __restrict__ patches,
                                                const float* __restrict__ db,
                                                const float* __restrict__ partial,
                                                const float* __restrict__ dbnorm,
                                                float* __restrict__ out) {
    int b = blockIdx.x;
    if (b < COPY_BLOCKS) {
        int e = b * 256 + threadIdx.x;          // 36864 float4 = 147456 floats
        ((float4*)out)[e] = ((const float4*)db)[e];
        return;
    }
    __shared__ int s_bn;
    __shared__ int s_blist[256];
    __shared__ float sp[WS9];
    __shared__ float snp;
    __shared__ int shit;

    int tid = (int)threadIdx.x;
    int i = (b - COPY_BLOCKS) * 256 + tid;
    if (tid == 0) s_bn = 0;
    __syncthreads();

    float cosmax = partial[i];
#pragma unroll
    for (int c = 1; c < JCH; c++)
        cosmax = fmaxf(cosmax, partial[(size_t)c * NPATCH + i]);
    if (cosmax >= BAND_LO && cosmax < BAND_HI) {
        int idx = atomicAdd(&s_bn, 1);
        s_blist[idx] = i;                       // rechecked below
    } else {
        int hit = (cosmax >= BAND_HI) ? 1 : 0;
#pragma unroll
        for (int k = 0; k < WS9; k++)
            out[(size_t)(NDB + i) * WS9 + k] = hit ? 0.0f : patches[(size_t)i * WS9 + k];
    }
    __syncthreads();
    int nb = s_bn;

    // exact numpy-mirror recheck (typically 0-2 entries per block)
    for (int e = 0; e < nb; e++) {
        int bi = s_blist[e];
        if (tid == 0) {
            float p[WS9];
            for (int k = 0; k < WS9; k++) { p[k] = patches[(size_t)bi * WS9 + k]; sp[k] = p[k]; }
            snp = np_norm9(p);
            shit = 0;
        }
        __syncthreads();
        float p[WS9];
#pragma unroll
        for (int k = 0; k < WS9; k++) p[k] = sp[k];
        float npn = snp;
        int hit = 0;
        for (int j = tid; j < NDB; j += 256) {
            float d[WS9];
#pragma unroll
            for (int k = 0; k < WS9; k++) d[k] = db[(size_t)j * WS9 + k];
            float dot = 0.0f;
#pragma unroll
            for (int k = 0; k < WS9; k++) dot = fmaf(p[k], d[k], dot);
            float cs = dot / (npn * dbnorm[j]);   // IEEE fp32 divide, exact norms
            if (!((double)cs < 0.9)) hit = 1;     // numpy promotes to f64
        }
        if (hit) atomicOr(&shit, 1);
        __syncthreads();
        int m = shit;
        if (tid < WS9)
            out[(size_t)(NDB + bi) * WS9 + tid] = m ? 0.0f : sp[tid];
        __syncthreads();
    }
}

extern "C" void kernel_launch(void* const* d_in, const int* in_sizes, int n_in,
                              void* d_out, int out_size, void* d_ws, size_t ws_size,
                              hipStream_t stream) {
    const float* patches = (const float*)d_in[0];  // [16384][9]
    const float* db      = (const float*)d_in[1];  // [16384][9]
    float* out = (float*)d_out;                    // [32768][9]

    // ws layout: partial (JCH*NPATCH f32 = 2 MB) | dbnorm (64 KB)
    char* wsb = (char*)d_ws;
    float* partial = (float*)wsb;
    float* dbnorm  = (float*)(wsb + (size_t)JCH * NPATCH * 4);

    k_phase1<<<dim3(NPATCH / PBLK, JCH), dim3(256), 0, stream>>>(patches, db,
                                                                 partial, dbnorm);
    k_finish<<<dim3(COPY_BLOCKS + NPATCH / 256), dim3(256), 0, stream>>>(
        patches, db, partial, dbnorm, out);
}

// Round 6
// 94.406 us; speedup vs baseline: 1.1060x; 1.0236x over previous
//
#include <hip/hip_runtime.h>

#define NPATCH 16384
#define NDB    16384
#define WS9    9
#define KP     16               // K padded 9 -> 16 for 32x32x16 MFMA
#define JCH    32               // db chunks (grid.y)
#define CHUNK  (NDB / JCH)      // 512 rows per chunk
#define TILES  (CHUNK / 32)     // 16 j-tiles per chunk
// Split-bf16 cosmax error vs numpy fp32 path <= ~6e-6 (lo*lo 3.8e-6 + accum
// 5e-7 + normalize 2e-7 + numpy's own ~1e-6). Band +-2e-5 keeps 3x margin;
// band population ~= 80 patches over 64 classify blocks -> in-block recheck
// is ~1-2 entries per block.
#define BAND_LO 0.89998f
#define BAND_HI 0.90002f
#define COPY_BLOCKS 144         // NDB*9/4/256 float4-copy blocks

typedef short bf16x8 __attribute__((ext_vector_type(8)));
typedef float f32x16 __attribute__((ext_vector_type(16)));

#define MAX3(a,b,c) fmaxf(fmaxf((a),(b)),(c))

// numpy-order norm of 9 elements: sqrt(pairwise-8 + remainder), no contraction.
__device__ __forceinline__ float np_norm9(const float* v) {
#pragma clang fp contract(off)
    float q0 = v[0] * v[0], q1 = v[1] * v[1], q2 = v[2] * v[2], q3 = v[3] * v[3];
    float q4 = v[4] * v[4], q5 = v[5] * v[5], q6 = v[6] * v[6], q7 = v[7] * v[7];
    float q8 = v[8] * v[8];
    float s = ((q0 + q1) + (q2 + q3)) + ((q4 + q5) + (q6 + q7));
    s = s + q8;
    return sqrtf(s);
}

// fp32 -> bf16 RTNE (no NaN inputs here), and back
__device__ __forceinline__ unsigned short f2bf(float x) {
    unsigned u = __float_as_uint(x);
    return (unsigned short)((u + 0x7fffu + ((u >> 16) & 1u)) >> 16);
}
__device__ __forceinline__ float bf2f(unsigned short h) {
    return __uint_as_float(((unsigned)h) << 16);
}

// load row of 9, normalize, split to bf16 hi/lo, K-pad to 16, pack to LDS as
// 2x int4 per array. Bit-identical to the proven R0 staging (absmax=0).
__device__ __forceinline__ void stage_row(const float* __restrict__ src,
                                          unsigned short* dh, unsigned short* dl) {
    float v[WS9];
#pragma unroll
    for (int k = 0; k < WS9; k++) v[k] = src[k];
    float inv = 1.0f / np_norm9(v);
    unsigned short h[KP], l[KP];
#pragma unroll
    for (int k = 0; k < KP; k++) {
        float x = (k < WS9) ? v[k] * inv : 0.0f;
        h[k] = f2bf(x);
        l[k] = f2bf(x - bf2f(h[k]));
    }
    int hw[8], lw[8];
#pragma unroll
    for (int k = 0; k < 8; k++) {
        hw[k] = (int)h[2 * k] | ((int)h[2 * k + 1] << 16);
        lw[k] = (int)l[2 * k] | ((int)l[2 * k + 1] << 16);
    }
    ((int4*)dh)[0] = make_int4(hw[0], hw[1], hw[2], hw[3]);
    ((int4*)dh)[1] = make_int4(hw[4], hw[5], hw[6], hw[7]);
    ((int4*)dl)[0] = make_int4(lw[0], lw[1], lw[2], lw[3]);
    ((int4*)dl)[1] = make_int4(lw[4], lw[5], lw[6], lw[7]);
}

// K1: fused prep + phase1 — VERBATIM the round-0 best-measured kernel body
// (95.38us config; only band_count init removed, band handling is now
// in-block in k_finish). Block = 256 patches (x) x 512-row db chunk (y).
// Splits in-block into LDS; dot = hi*hi + hi*lo + lo*hi via 32x32x16 bf16
// MFMA; chunk cos-max plain-stored to partial[y][i] (no atomics, no init).
__global__ __launch_bounds__(256) void k_phase1(const float* __restrict__ patches,
                                                const float* __restrict__ db,
                                                float* __restrict__ partial) {
    __shared__ __align__(16) unsigned short s_dnh[CHUNK * KP];
    __shared__ __align__(16) unsigned short s_dnl[CHUNK * KP];
    __shared__ __align__(16) unsigned short s_pnh[256 * KP];
    __shared__ __align__(16) unsigned short s_pnl[256 * KP];

    int jbase = blockIdx.y * CHUNK;
    int ibase = blockIdx.x * 256;
#pragma unroll
    for (int rr = 0; rr < CHUNK / 256; rr++) {
        int r = rr * 256 + threadIdx.x;
        stage_row(db + (size_t)(jbase + r) * WS9, &s_dnh[r * KP], &s_dnl[r * KP]);
    }
    stage_row(patches + (size_t)(ibase + threadIdx.x) * WS9,
              &s_pnh[threadIdx.x * KP], &s_pnl[threadIdx.x * KP]);
    __syncthreads();

    int lane = threadIdx.x & 63;
    int wave = threadIdx.x >> 6;
    int col = lane & 31;
    int half = lane >> 5;
    int i0 = ibase + wave * 64;

    const bf16x8* Ph = (const bf16x8*)s_pnh;   // 2 frags per 16-elem row
    const bf16x8* Pl = (const bf16x8*)s_pnl;
    bf16x8 b_hi0 = Ph[(wave * 64 + col) * 2 + half];
    bf16x8 b_lo0 = Pl[(wave * 64 + col) * 2 + half];
    bf16x8 b_hi1 = Ph[(wave * 64 + 32 + col) * 2 + half];
    bf16x8 b_lo1 = Pl[(wave * 64 + 32 + col) * 2 + half];

    const bf16x8* Ah = (const bf16x8*)s_dnh;
    const bf16x8* Al = (const bf16x8*)s_dnl;

    f32x16 zc = {0.f,0.f,0.f,0.f,0.f,0.f,0.f,0.f,0.f,0.f,0.f,0.f,0.f,0.f,0.f,0.f};
    float rm0 = -3.0e38f, rm1 = -3.0e38f;

#pragma unroll 2
    for (int t = 0; t < TILES; ++t) {
        bf16x8 a_h = Ah[(t * 32 + col) * 2 + half];
        bf16x8 a_l = Al[(t * 32 + col) * 2 + half];
        f32x16 acc0 = __builtin_amdgcn_mfma_f32_32x32x16_bf16(a_h, b_hi0, zc, 0, 0, 0);
        acc0 = __builtin_amdgcn_mfma_f32_32x32x16_bf16(a_h, b_lo0, acc0, 0, 0, 0);
        acc0 = __builtin_amdgcn_mfma_f32_32x32x16_bf16(a_l, b_hi0, acc0, 0, 0, 0);
        f32x16 acc1 = __builtin_amdgcn_mfma_f32_32x32x16_bf16(a_h, b_hi1, zc, 0, 0, 0);
        acc1 = __builtin_amdgcn_mfma_f32_32x32x16_bf16(a_h, b_lo1, acc1, 0, 0, 0);
        acc1 = __builtin_amdgcn_mfma_f32_32x32x16_bf16(a_l, b_hi1, acc1, 0, 0, 0);
        // max3-fusable tree (max associative: same result as serial chain)
        {
            float u0 = MAX3(acc0[0],  acc0[1],  acc0[2]);
            float u1 = MAX3(acc0[3],  acc0[4],  acc0[5]);
            float u2 = MAX3(acc0[6],  acc0[7],  acc0[8]);
            float u3 = MAX3(acc0[9],  acc0[10], acc0[11]);
            float u4 = MAX3(acc0[12], acc0[13], acc0[14]);
            float u5 = MAX3(u0, u1, acc0[15]);
            float u6 = MAX3(u2, u3, u4);
            rm0 = MAX3(u5, u6, rm0);
        }
        {
            float u0 = MAX3(acc1[0],  acc1[1],  acc1[2]);
            float u1 = MAX3(acc1[3],  acc1[4],  acc1[5]);
            float u2 = MAX3(acc1[6],  acc1[7],  acc1[8]);
            float u3 = MAX3(acc1[9],  acc1[10], acc1[11]);
            float u4 = MAX3(acc1[12], acc1[13], acc1[14]);
            float u5 = MAX3(u0, u1, acc1[15]);
            float u6 = MAX3(u2, u3, u4);
            rm1 = MAX3(u5, u6, rm1);
        }
    }
    rm0 = fmaxf(rm0, __shfl_xor(rm0, 32, 64));
    rm1 = fmaxf(rm1, __shfl_xor(rm1, 32, 64));
    int ti = half ? (i0 + 32 + col) : (i0 + col);
    partial[(size_t)blockIdx.y * NPATCH + ti] = half ? rm1 : rm0;
}

// K2: merged finish. Blocks [0,144): db->out float4 copy. Blocks [144,208):
// classify 256 patches (max over 32 chunk-partials), write definite rows,
// recheck this block's own band entries inline with the exact numpy-mirror
// path (recomputing np_norm9(d) per row — identical math to the proven R0
// k_phase2, absmax=0).
__global__ __launch_bounds__(256) void k_finish(const float* __restrict__ patches,
                                                const float* __restrict__ db,
                                                const float* __restrict__ partial,
                                                float* __restrict__ out) {
    int b = blockIdx.x;
    if (b < COPY_BLOCKS) {
        int e = b * 256 + threadIdx.x;          // 36864 float4 = 147456 floats
        ((float4*)out)[e] = ((const float4*)db)[e];
        return;
    }
    __shared__ int s_bn;
    __shared__ int s_blist[256];
    __shared__ float sp[WS9];
    __shared__ float snp;
    __shared__ int shit;

    int tid = (int)threadIdx.x;
    int i = (b - COPY_BLOCKS) * 256 + tid;
    if (tid == 0) s_bn = 0;
    __syncthreads();

    float cosmax = partial[i];
#pragma unroll
    for (int c = 1; c < JCH; c++)
        cosmax = fmaxf(cosmax, partial[(size_t)c * NPATCH + i]);
    if (cosmax >= BAND_LO && cosmax < BAND_HI) {
        int idx = atomicAdd(&s_bn, 1);
        s_blist[idx] = i;                       // rechecked below
    } else {
        int hit = (cosmax >= BAND_HI) ? 1 : 0;
#pragma unroll
        for (int k = 0; k < WS9; k++)
            out[(size_t)(NDB + i) * WS9 + k] = hit ? 0.0f : patches[(size_t)i * WS9 + k];
    }
    __syncthreads();
    int nb = s_bn;

    // exact numpy-mirror recheck (typically 0-2 entries per block)
    for (int e = 0; e < nb; e++) {
        int bi = s_blist[e];
        if (tid == 0) {
            float p[WS9];
            for (int k = 0; k < WS9; k++) { p[k] = patches[(size_t)bi * WS9 + k]; sp[k] = p[k]; }
            snp = np_norm9(p);
            shit = 0;
        }
        __syncthreads();
        float p[WS9];
#pragma unroll
        for (int k = 0; k < WS9; k++) p[k] = sp[k];
        float npn = snp;
        int hit = 0;
        for (int j = tid; j < NDB; j += 256) {
            float d[WS9];
#pragma unroll
            for (int k = 0; k < WS9; k++) d[k] = db[(size_t)j * WS9 + k];
            float dot = 0.0f;
#pragma unroll
            for (int k = 0; k < WS9; k++) dot = fmaf(p[k], d[k], dot);
            float nd = np_norm9(d);
            float cs = dot / (npn * nd);          // IEEE fp32 divide
            if (!((double)cs < 0.9)) hit = 1;     // numpy promotes to f64
        }
        if (hit) atomicOr(&shit, 1);
        __syncthreads();
        int m = shit;
        if (tid < WS9)
            out[(size_t)(NDB + bi) * WS9 + tid] = m ? 0.0f : sp[tid];
        __syncthreads();
    }
}

extern "C" void kernel_launch(void* const* d_in, const int* in_sizes, int n_in,
                              void* d_out, int out_size, void* d_ws, size_t ws_size,
                              hipStream_t stream) {
    const float* patches = (const float*)d_in[0];  // [16384][9]
    const float* db      = (const float*)d_in[1];  // [16384][9]
    float* out = (float*)d_out;                    // [32768][9]

    // ws layout: partial (JCH*NPATCH f32 = 2 MB)
    float* partial = (float*)d_ws;

    k_phase1<<<dim3(NPATCH / 256, JCH), dim3(256), 0, stream>>>(patches, db, partial);
    k_finish<<<dim3(COPY_BLOCKS + NPATCH / 256), dim3(256), 0, stream>>>(
        patches, db, partial, out);
}